// Round 6
// baseline (757.367 us; speedup 1.0000x reference)
//
#include <hip/hip_runtime.h>

// ---------------------------------------------------------------------------
// DistributionShiftGAT: 3-layer GAT on MI355X (gfx950).
// R17: CSR rebuilt in degree-sorted space. R16 sequentialized node-indexed
//      streams but FETCH stayed 87MB: the csr edge array itself was still in
//      ORIGINAL dst order while nodes are processed in SORTED order -> 30000
//      random ~68B row-segment touches per XCD (~5MB/XCD line traffic vs 2MB
//      sequential, +24MB total) AND a permuted-csr miss sits at the head of
//      the dependent chain (csr -> gather -> FMA), serializing ~600cy before
//      each gather. R17 builds row_ptr_s/csr in sorted space (second scan
//      over rank-ordered degrees; scatter cursors via inv[dst]); agg reads
//      row_ptr_s[ni] directly (node_order gone from hot path) and streams
//      csr sequentially. Layer-3 d_out scatter keeps node_order. All else
//      identical to R16 (slice=blockIdx%8, group-per-node, depth-4 gathers).
// ---------------------------------------------------------------------------

#define NEG_SLOPE 0.2f

typedef __attribute__((ext_vector_type(8))) short short8;
typedef __attribute__((ext_vector_type(4))) float floatx4;
typedef __attribute__((ext_vector_type(4))) unsigned uintx4;

static __device__ __forceinline__ unsigned short f2bf(float f) {
    unsigned u = __float_as_uint(f);
    u = u + 0x7FFFu + ((u >> 16) & 1u);      // RNE
    return (unsigned short)(u >> 16);
}
static __device__ __forceinline__ float bf2f_lo(unsigned u) {
    return __uint_as_float(u << 16);
}
static __device__ __forceinline__ float bf2f_hi(unsigned u) {
    return __uint_as_float(u & 0xFFFF0000u);
}

// async global->LDS, 16B per lane; LDS fills base + lane*16 (wave-uniform base)
static __device__ __forceinline__ void async_copy16(const void* g, void* l) {
    __builtin_amdgcn_global_load_lds(
        (const __attribute__((address_space(1))) unsigned int*)g,
        (__attribute__((address_space(3))) unsigned int*)l, 16, 0, 0);
}

// ---------------- prep: W transposes + edge histogram -----------------------
// cursor (and dhist after it) must be zeroed before this kernel.

__global__ __launch_bounds__(256)
void prep_hist_kernel(const float* __restrict__ W1, unsigned short* __restrict__ W1T,
                      const float* __restrict__ W2, unsigned short* __restrict__ W2T,
                      const float* __restrict__ W3, unsigned short* __restrict__ W3T,
                      const int* __restrict__ ei, int* cursor, int E) {
    int j = blockIdx.x * 256 + threadIdx.x;
    if (j < 256 * 512) {                       // W1 [256,512] -> W1T [512,256]
        int k = j >> 9, n = j & 511;
        W1T[(size_t)n * 256 + k] = f2bf(W1[j]);
        return;
    }
    j -= 256 * 512;
    if (j < 512 * 512) {                       // W2 [512,512] -> W2T [512,512]
        int k = j >> 9, n = j & 511;
        W2T[(size_t)n * 512 + k] = f2bf(W2[j]);
        return;
    }
    j -= 512 * 512;
    if (j < 512 * 128) {                       // W3 [512,128] -> W3T [128,512]
        int k = j >> 7, n = j & 127;
        W3T[(size_t)n * 512 + k] = f2bf(W3[j]);
        return;
    }
    j -= 512 * 128;
    if (j < E) atomicAdd(&cursor[ei[E + j]], 1);   // histogram of dst
}

// ---------------- CSR scan (self-loops folded: row_ptr[i]=edge_prefix+i) ----
// Generic: input counts in `cnt`, outputs row_ptr (+N self-loop slots) and
// leaves cnt[i] = row_ptr[i] (write cursor). Also accumulates a degree
// histogram into dhist (used only on the first pass; scratch on the second).

__global__ __launch_bounds__(1024)
void scan_bsum_kernel(const int* __restrict__ cnt, int* __restrict__ bsum, int N) {
    __shared__ int wsum[16];
    int tid = threadIdx.x, lane = tid & 63, w = tid >> 6;
    int i = blockIdx.x * 1024 + tid;
    int v = (i < N) ? cnt[i] : 0;
    #pragma unroll
    for (int off = 32; off; off >>= 1) v += __shfl_xor(v, off, 64);
    if (lane == 0) wsum[w] = v;
    __syncthreads();
    if (tid == 0) {
        int t = 0;
        #pragma unroll
        for (int k = 0; k < 16; ++k) t += wsum[k];
        bsum[blockIdx.x] = t;
    }
}

__global__ __launch_bounds__(1024)
void scan_final_kernel(int* __restrict__ cnt, const int* __restrict__ bsum,
                       int* __restrict__ row_ptr, int* __restrict__ dhist,
                       int N, int NB) {
    __shared__ int wsum[16];
    __shared__ int boff_sh;
    int tid = threadIdx.x, lane = tid & 63, w = tid >> 6;
    if (w == 0) {
        int bv = (lane < NB) ? bsum[lane] : 0;
        int bx = bv;
        #pragma unroll
        for (int off = 1; off < 64; off <<= 1) {
            int t = __shfl_up(bx, off, 64);
            if (lane >= off) bx += t;
        }
        if (lane == blockIdx.x) boff_sh = bx - bv;       // exclusive prefix
        if (blockIdx.x == 0 && lane == 63) row_ptr[N] = bx + N;  // +N self-loops
    }
    int i = blockIdx.x * 1024 + tid;
    int v = (i < N) ? cnt[i] : 0;
    if (i < N) atomicAdd(&dhist[v < 511 ? v : 511], 1);  // edge-degree histogram
    int x = v;
    #pragma unroll
    for (int off = 1; off < 64; off <<= 1) {
        int t = __shfl_up(x, off, 64);
        if (lane >= off) x += t;
    }
    if (lane == 63) wsum[w] = x;
    __syncthreads();
    if (w == 0 && lane < 16) {
        int y = wsum[lane];
        #pragma unroll
        for (int off = 1; off < 16; off <<= 1) {
            int t = __shfl_up(y, off, 64);
            if (lane >= off) y += t;
        }
        wsum[lane] = y;
    }
    __syncthreads();
    int woff = (w == 0) ? 0 : wsum[w - 1];
    int ex = boff_sh + woff + x - v + i;     // + i = self-loop slots
    if (i < N) { row_ptr[i] = ex; cnt[i] = ex; }
}

// exclusive prefix over the 512-bin degree histogram (1 block, 512 threads)
__global__ __launch_bounds__(512)
void deg_scan_kernel(const int* __restrict__ dhist, int* __restrict__ dcur) {
    __shared__ int ws[8];
    int tid = threadIdx.x, lane = tid & 63, w = tid >> 6;
    int v = dhist[tid];
    int x = v;
    #pragma unroll
    for (int off = 1; off < 64; off <<= 1) {
        int t = __shfl_up(x, off, 64);
        if (lane >= off) x += t;
    }
    if (lane == 63) ws[w] = x;
    __syncthreads();
    if (w == 0 && lane < 8) {
        int y = ws[lane];
        #pragma unroll
        for (int off = 1; off < 8; off <<= 1) {
            int t = __shfl_up(y, off, 64);
            if (lane >= off) y += t;
        }
        ws[lane] = y;
    }
    __syncthreads();
    int woff = (w == 0) ? 0 : ws[w - 1];
    dcur[tid] = woff + x - v;                // exclusive prefix
}

// degree-sorted ranking: node_order[rank]=node, inv_order[node]=rank,
// sdeg[rank] = edge-degree (input for the second, sorted-space scan)
__global__ __launch_bounds__(256)
void rank_kernel(const int* __restrict__ row_ptr, int* __restrict__ dcur,
                 int* __restrict__ node_order, int* __restrict__ inv_order,
                 int* __restrict__ sdeg, int N) {
    int n = blockIdx.x * 256 + threadIdx.x;
    if (n < N) {
        int d = row_ptr[n + 1] - row_ptr[n] - 1;     // edge-degree
        int pos = atomicAdd(&dcur[d < 511 ? d : 511], 1);
        node_order[pos] = n;
        inv_order[n] = pos;
        sdeg[pos] = d;
    }
}

// edge scatter into SORTED-space csr (cursors = sdeg after 2nd scan) + x cast
__global__ __launch_bounds__(256)
void scatter_xcast_kernel(const int* __restrict__ ei, int* scur,
                          int* __restrict__ csr_src,
                          const int* __restrict__ node_order,
                          const int* __restrict__ inv_order,
                          const float* __restrict__ x,
                          unsigned short* __restrict__ x_bf,
                          int E, int N) {
    int i = blockIdx.x * 256 + threadIdx.x;
    if (i < E) {
        int s = ei[i], d = ei[E + i];
        int pos = atomicAdd(&scur[inv_order[d]], 1);
        csr_src[pos] = inv_order[s];
    } else if (i < E + N) {
        int n = i - E;
        int pos = atomicAdd(&scur[inv_order[n]], 1);
        csr_src[pos] = inv_order[n];     // self loop
    } else if (i < E + N + N * 64) {     // x: [N,256]f32 -> permuted bf16
        int j = i - E - N;
        int ip = j >> 6, c4 = j & 63;    // dst row (sorted space), float4 col
        int node = node_order[ip];
        float4 v = ((const float4*)x)[(size_t)node * 64 + c4];
        ushort4 o;
        o.x = f2bf(v.x); o.y = f2bf(v.y); o.z = f2bf(v.z); o.w = f2bf(v.w);
        ((ushort4*)x_bf)[(size_t)ip * 64 + c4] = o;
    }
}

// ---------------- bf16 MFMA GEMM + fused attention dots ----------------
// C[M,Nn]bf16 = A[M,K]bf16 @ BT[Nn,K]^T. TMxTN tile, BK=64, 8 waves (512 thr),
// 64x64 wave tiles. A+B staged into one LDS buffer via global_load_lds
// 16B/lane; phys seg = seg ^ (row&7) keeps staging and b128 reads bank-
// minimal. Rows in permuted (degree-sorted) space; GEMM is order-agnostic.
// Epilogue computes a_src/a_dst (layout [H][N], permuted space).

template<int TM, int TN>
__global__ __launch_bounds__(512)
void mfma_gemm_kernel(const unsigned short* __restrict__ A,
                      const unsigned short* __restrict__ BT,
                      unsigned short* __restrict__ C,
                      const float* __restrict__ att_src,
                      const float* __restrict__ att_dst,
                      float* __restrict__ a_srcO, float* __restrict__ a_dstO,
                      int H, int M, int Nn, int K) {
    constexpr int NH = TN / 128;               // heads per block
    __shared__ unsigned short buf[(TM + TN) * 64];    // 48 KB
    __shared__ float psum[TN / 64][TM];
    __shared__ float pdsum[TN / 64][TM];
    const int tid = threadIdx.x;
    const int m0 = blockIdx.y * TM;
    const int n0 = blockIdx.x * TN;
    const int head_base = blockIdx.x * NH;
    const int lane = tid & 63, wave = tid >> 6;        // wave 0..7
    const int wm = (wave & (TM / 64 - 1)) * 64;
    const int wn = (wave / (TM / 64)) * 64;
    const int quad = lane >> 4, rr = lane & 15;

    // staging: 8 waves x 6 insts x 8 rows = 384 rows (TM A-rows + TN B-rows)
    const int srow = lane >> 3;                // row within 8-row group
    const int sseg = (lane & 7) ^ srow;        // logical 8-elem seg to fetch
    const unsigned short* gptr[6];
    unsigned short* lptr[6];
    #pragma unroll
    for (int j = 0; j < 6; ++j) {
        int base_row = wave * 48 + j * 8;      // multiple of 8; A/B uniform
        lptr[j] = buf + base_row * 64;
        if (base_row < TM) {
            int gr = min(m0 + base_row + srow, M - 1);
            gptr[j] = A + (size_t)gr * K;
        } else {
            int gr = n0 + (base_row - TM) + srow;
            gptr[j] = BT + (size_t)gr * K;
        }
    }

    floatx4 acc[4][4] = {};

    for (int k0 = 0; k0 < K; k0 += 64) {
        #pragma unroll
        for (int j = 0; j < 6; ++j)
            async_copy16(gptr[j] + k0 + sseg * 8, lptr[j]);
        __syncthreads();

        #pragma unroll
        for (int k32 = 0; k32 < 2; ++k32) {
            short8 af[4], bf[4];
            #pragma unroll
            for (int mi = 0; mi < 4; ++mi) {
                int row = wm + mi * 16 + rr;
                int phys = (k32 * 4 + quad) ^ (rr & 7);
                af[mi] = *(const short8*)(buf + row * 64 + phys * 8);
            }
            #pragma unroll
            for (int ni = 0; ni < 4; ++ni) {
                int row = TM + wn + ni * 16 + rr;
                int phys = (k32 * 4 + quad) ^ (rr & 7);
                bf[ni] = *(const short8*)(buf + row * 64 + phys * 8);
            }
            #pragma unroll
            for (int mi = 0; mi < 4; ++mi)
                #pragma unroll
                for (int ni = 0; ni < 4; ++ni)
                    acc[mi][ni] = __builtin_amdgcn_mfma_f32_16x16x32_bf16(
                        af[mi], bf[ni], acc[mi][ni], 0, 0, 0);
        }
        __syncthreads();
    }

    // ---- h store (bf16), C/D layout: col=lane&15, row=quad*4+reg ----
    #pragma unroll
    for (int mi = 0; mi < 4; ++mi) {
        #pragma unroll
        for (int ni = 0; ni < 4; ++ni) {
            int col = n0 + wn + ni * 16 + rr;
            #pragma unroll
            for (int r = 0; r < 4; ++r) {
                int row = m0 + wm + mi * 16 + quad * 4 + r;
                if (row < M) C[(size_t)row * Nn + col] = f2bf(acc[mi][ni][r]);
            }
        }
    }

    // ---- fused attention dots (per covered head) ----
    float ats[4], atd[4];
    #pragma unroll
    for (int ni = 0; ni < 4; ++ni) {
        int cc = wn + ni * 16;                  // col within block tile
        int h = head_base + (cc >> 7);
        int c = (cc + rr) & 127;                // channel within head
        ats[ni] = att_src[h * 128 + c];
        atd[ni] = att_dst[h * 128 + c];
    }
    const int wg = wn >> 6;                     // wave column group
    #pragma unroll
    for (int mi = 0; mi < 4; ++mi) {
        #pragma unroll
        for (int r = 0; r < 4; ++r) {
            float ps = 0.f, pd = 0.f;
            #pragma unroll
            for (int ni = 0; ni < 4; ++ni) {
                ps += ats[ni] * acc[mi][ni][r];
                pd += atd[ni] * acc[mi][ni][r];
            }
            #pragma unroll
            for (int off = 1; off < 16; off <<= 1) {
                ps += __shfl_xor(ps, off, 64);
                pd += __shfl_xor(pd, off, 64);
            }
            if (rr == 0) {
                int row = wm + mi * 16 + quad * 4 + r;   // local row
                psum[wg][row] = ps;
                pdsum[wg][row] = pd;
            }
        }
    }
    __syncthreads();
    if (tid < NH * TM) {
        int h = tid / TM, r = tid % TM;
        int gr = m0 + r;
        if (gr < M) {
            // [H][N] layout, permuted space (rows already sorted)
            a_srcO[(size_t)(head_base + h) * M + gr] = psum[2 * h][r] + psum[2 * h + 1][r];
            a_dstO[(size_t)(head_base + h) * M + gr] = pdsum[2 * h][r] + pdsum[2 * h + 1][r];
        }
    }
}

// ---------------- XCD-sliced group-per-node softmax + aggregation -----------
// FULLY sorted space: row_ptr_s indexed by position (sequential), csr rows
// laid out in processing order (sequential stream per XCD; head of the
// dependent chain is now an L1/L2 hit), a_dst/outputs sequential; only the
// feature/a_src gathers are scattered (slice L2-resident: N*128B = 3.84MB).
// Slice s = blockIdx%NSLICE fixed. 8-lane group owns one node's 128B slice,
// depth-4 pipelined gather, zero shuffles; sorted order -> uniform degree
// per wave. Layer 3 (BF16OUT=false) scatters fp32 rows to d_out via
// node_order (original order), once.

template<int F, int H, int NSLICE, bool RELU, bool BF16OUT>
__global__ __launch_bounds__(256)
void agg_kernel(const unsigned* __restrict__ hfeat, const float* __restrict__ a_src,
                const float* __restrict__ a_dst, const int* __restrict__ row_ptr_s,
                const int* __restrict__ csr_src, const int* __restrict__ node_order,
                const float* __restrict__ bias, void* __restrict__ out_v, int N) {
    constexpr int RU = F / 2;                // uints per feature row
    constexpr int SU = RU / NSLICE;          // uints per slice (32 -> 128B)
    constexpr int GS = SU / 4;               // lanes per group (8)
    constexpr int GPW = 64 / GS;             // nodes per wave (8)
    constexpr int FS = F / NSLICE;           // feats per slice (64)
    static_assert(GS == 8, "group size must be 8");
    const int lane = threadIdx.x & 63, wave = threadIdx.x >> 6;
    const int s = blockIdx.x % NSLICE;       // FIXED slice -> XCD affinity
    const int g = lane >> 3, l = lane & 7;
    int ni = ((blockIdx.x / NSLICE) * 4 + wave) * GPW + g;   // sorted position
    ni = ni < N ? ni : N - 1;                // dup tail: same bytes, benign
    const int begin = row_ptr_s[ni];
    const int deg = row_ptr_s[ni + 1] - begin;     // >= 1 (self-loop)
    const int h = (s * FS) / (F / H);
    const float adst = a_dst[(size_t)h * N + ni];  // permuted, sequential
    const unsigned* __restrict__ sbase = hfeat + (size_t)s * SU + l * 4;
    const float* __restrict__ asrc_h = a_src + (size_t)h * N;
    const int* __restrict__ crow = csr_src + begin;

    int maxd = deg;                          // max degree across the 8 groups
    #pragma unroll
    for (int off = 8; off < 64; off <<= 1) {
        int t = __shfl_xor(maxd, off, 64);
        maxd = t > maxd ? t : maxd;
    }

    float acc[8] = {};
    float dacc = 0.f;
    uintx4 u0, u1, u2, u3;
    float av0, av1, av2, av3;

#define LOADSLOT(idx, U, AV)                                                  \
    {                                                                         \
        int e_ = (idx) < deg ? (idx) : deg - 1;                               \
        int src_ = __builtin_nontemporal_load(crow + e_);   /* position */    \
        U = *(const uintx4*)(sbase + (size_t)src_ * RU);                      \
        AV = asrc_h[src_];                                                    \
    }

#define CONSUME(idx, U, AV)                                                   \
    {                                                                         \
        float e_ = AV + adst;                                                 \
        e_ = fmaxf(e_, NEG_SLOPE * e_);                                       \
        float ex_ = ((idx) < deg) ? __expf(e_) : 0.f;                         \
        dacc += ex_;                                                          \
        _Pragma("unroll")                                                     \
        for (int q_ = 0; q_ < 4; ++q_) {                                      \
            acc[2 * q_]     += ex_ * bf2f_lo(U[q_]);                          \
            acc[2 * q_ + 1] += ex_ * bf2f_hi(U[q_]);                          \
        }                                                                     \
    }

    LOADSLOT(0, u0, av0);
    LOADSLOT(1, u1, av1);
    LOADSLOT(2, u2, av2);
    LOADSLOT(3, u3, av3);
    int i = 0;
    for (; i + 4 < maxd; i += 4) {
        CONSUME(i,     u0, av0); LOADSLOT(i + 4, u0, av0);
        CONSUME(i + 1, u1, av1); LOADSLOT(i + 5, u1, av1);
        CONSUME(i + 2, u2, av2); LOADSLOT(i + 6, u2, av2);
        CONSUME(i + 3, u3, av3); LOADSLOT(i + 7, u3, av3);
    }
    CONSUME(i,     u0, av0);
    CONSUME(i + 1, u1, av1);
    CONSUME(i + 2, u2, av2);
    CONSUME(i + 3, u3, av3);
#undef LOADSLOT
#undef CONSUME

    // each lane of a group holds the full denom and its 8 features
    float inv = 1.f / dacc;
    const int cb = s * FS + l * 8;           // feature base of this lane
    float v[8];
    #pragma unroll
    for (int j = 0; j < 8; ++j) {
        float t = acc[j] * inv + bias[cb + j];
        v[j] = RELU ? fmaxf(t, 0.f) : t;
    }
    if (BF16OUT) {
        uintx4 pk;
        #pragma unroll
        for (int q = 0; q < 4; ++q)
            pk[q] = (unsigned)f2bf(v[2 * q]) | ((unsigned)f2bf(v[2 * q + 1]) << 16);
        __builtin_nontemporal_store(pk,                       // permuted, seq
            (uintx4*)((unsigned*)out_v + (size_t)ni * RU + s * SU + l * 4));
    } else {
        const int node = node_order[ni];                      // original order
        floatx4 o0 = {v[0], v[1], v[2], v[3]};
        floatx4 o1 = {v[4], v[5], v[6], v[7]};
        float* dst = (float*)out_v + (size_t)node * F + cb;
        __builtin_nontemporal_store(o0, (floatx4*)dst);
        __builtin_nontemporal_store(o1, (floatx4*)(dst + 4));
    }
}

// ---------------- host launch ----------------

extern "C" void kernel_launch(void* const* d_in, const int* in_sizes, int n_in,
                              void* d_out, int out_size, void* d_ws, size_t ws_size,
                              hipStream_t stream) {
    const float* x        = (const float*)d_in[0];
    const int*   ei       = (const int*)  d_in[1];
    const float* W1       = (const float*)d_in[2];
    const float* att_src1 = (const float*)d_in[3];
    const float* att_dst1 = (const float*)d_in[4];
    const float* b1       = (const float*)d_in[5];
    const float* W2       = (const float*)d_in[6];
    const float* att_src2 = (const float*)d_in[7];
    const float* att_dst2 = (const float*)d_in[8];
    const float* b2       = (const float*)d_in[9];
    const float* W3       = (const float*)d_in[10];
    const float* att_src3 = (const float*)d_in[11];
    const float* att_dst3 = (const float*)d_in[12];
    const float* b3       = (const float*)d_in[13];

    const int IN_FEATS = 256;
    const int N = in_sizes[0] / IN_FEATS;   // 30000
    const int E = in_sizes[1] / 2;          // 480000
    const int ET = E + N;
    const int NB = (N + 1023) / 1024;       // scan blocks (30)

    // workspace layout
    char* p = (char*)d_ws;
    unsigned short* h_bf    = (unsigned short*)p; p += (size_t)N * 512 * sizeof(unsigned short);
    unsigned short* act_bf  = (unsigned short*)p; p += (size_t)N * 512 * sizeof(unsigned short);
    unsigned short* x_bf    = (unsigned short*)p; p += (size_t)N * 256 * sizeof(unsigned short);
    float*          a_src   = (float*)p;          p += (size_t)N * 4 * sizeof(float);
    float*          a_dst   = (float*)p;          p += (size_t)N * 4 * sizeof(float);
    unsigned short* W1T     = (unsigned short*)p; p += (size_t)512 * 256 * sizeof(unsigned short);
    unsigned short* W2T     = (unsigned short*)p; p += (size_t)512 * 512 * sizeof(unsigned short);
    unsigned short* W3T     = (unsigned short*)p; p += (size_t)128 * 512 * sizeof(unsigned short);
    int*            row_ptr = (int*)p;            p += ((size_t)N + 16) * sizeof(int);   // original space
    int*            row_ptr_s = (int*)p;          p += ((size_t)N + 16) * sizeof(int);   // sorted space
    int*            cursor  = (int*)p;            p += (size_t)N * sizeof(int);
    int*            dhist   = (int*)p;            p += 512 * sizeof(int);
    int*            dhist2  = (int*)p;            p += 512 * sizeof(int);   // scratch
    int*            dcur    = (int*)p;            p += 512 * sizeof(int);
    int*            node_order = (int*)p;         p += (size_t)N * sizeof(int);
    int*            inv_order  = (int*)p;         p += (size_t)N * sizeof(int);
    int*            sdeg    = (int*)p;            p += (size_t)N * sizeof(int);
    int*            bsum    = (int*)p;            p += 64 * sizeof(int);
    int*            csr_src = (int*)p;            p += (size_t)ET * sizeof(int);

    // ---- prep: W transposes + hist; CSR build (orig) -> rank -> CSR (sorted)
    hipMemsetAsync(cursor, 0, ((size_t)N + 1024) * sizeof(int), stream); // cursor+dhist+dhist2
    {
        int total = 256 * 512 + 512 * 512 + 512 * 128 + E;
        prep_hist_kernel<<<(total + 255) / 256, 256, 0, stream>>>(
            W1, W1T, W2, W2T, W3, W3T, ei, cursor, E);
    }
    scan_bsum_kernel<<<NB, 1024, 0, stream>>>(cursor, bsum, N);
    scan_final_kernel<<<NB, 1024, 0, stream>>>(cursor, bsum, row_ptr, dhist, N, NB);
    deg_scan_kernel<<<1, 512, 0, stream>>>(dhist, dcur);
    rank_kernel<<<(N + 255) / 256, 256, 0, stream>>>(row_ptr, dcur, node_order, inv_order, sdeg, N);
    // second scan: sorted-space row_ptr_s + write cursors (sdeg -> cursors)
    scan_bsum_kernel<<<NB, 1024, 0, stream>>>(sdeg, bsum, N);
    scan_final_kernel<<<NB, 1024, 0, stream>>>(sdeg, bsum, row_ptr_s, dhist2, N, NB);
    {
        int total = E + N + N * 64;          // edges + self-loops + x float4s
        scatter_xcast_kernel<<<(total + 255) / 256, 256, 0, stream>>>(
            ei, sdeg, csr_src, node_order, inv_order, x, x_bf, E, N);
    }

    const int MB128 = (N + 127) / 128;      // 235
    const int MB256 = (N + 255) / 256;      // 118
    const int NC32 = (N + 31) / 32;         // node chunks (32 nodes/block)

    // ---- Layer 1: 256 -> 4x128 concat + relu (h bf16, permuted space) ----
    mfma_gemm_kernel<128, 256><<<dim3(2, MB128), 512, 0, stream>>>(x_bf, W1T, h_bf, att_src1, att_dst1, a_src, a_dst, 4, N, 512, 256);
    agg_kernel<512, 4, 8, true, true><<<8 * NC32, 256, 0, stream>>>((const unsigned*)h_bf, a_src, a_dst, row_ptr_s, csr_src, node_order, b1, act_bf, N);

    // ---- Layer 2: 512 -> 4x128 concat + relu (h bf16, permuted space) ----
    mfma_gemm_kernel<128, 256><<<dim3(2, MB128), 512, 0, stream>>>(act_bf, W2T, h_bf, att_src2, att_dst2, a_src, a_dst, 4, N, 512, 512);
    agg_kernel<512, 4, 8, true, true><<<8 * NC32, 256, 0, stream>>>((const unsigned*)h_bf, a_src, a_dst, row_ptr_s, csr_src, node_order, b2, act_bf, N);

    // ---- Layer 3: 512 -> 1x128 (h bf16), fp32 out (original order), no relu ----
    mfma_gemm_kernel<256, 128><<<dim3(1, MB256), 512, 0, stream>>>(act_bf, W3T, h_bf, att_src3, att_dst3, a_src, a_dst, 1, N, 128, 512);
    agg_kernel<128, 1, 2, false, false><<<2 * NC32, 256, 0, stream>>>((const unsigned*)h_bf, a_src, a_dst, row_ptr_s, csr_src, node_order, b3, d_out, N);
}

// Round 7
// 493.318 us; speedup vs baseline: 1.5353x; 1.5353x over previous
//
#include <hip/hip_runtime.h>

// ---------------------------------------------------------------------------
// DistributionShiftGAT: 3-layer GAT on MI355X (gfx950).
// R18: (a) scan decontamination: R17's 184us top dispatch was scan_final's
//      degree-histogram atomicAdd on SORTED input (all 1024 threads/block on
//      one address -> serialized). Histogram moved to a dedicated LDS-
//      privatized kernel; both scans are now pure (no global atomics).
//      (b) within-run A/B: layer-1 agg = R17 XCD-sliced group-per-node;
//      layer-2 agg = R11-proven full-row wave-per-node (75us at baseline),
//      ported to sorted space + [H][N] a-vectors. Profile shows both ->
//      next round adopts the winner. Layer-3 stays sliced (NSLICE=2).
// ---------------------------------------------------------------------------

#define NEG_SLOPE 0.2f

typedef __attribute__((ext_vector_type(8))) short short8;
typedef __attribute__((ext_vector_type(4))) float floatx4;
typedef __attribute__((ext_vector_type(4))) unsigned uintx4;

static __device__ __forceinline__ unsigned short f2bf(float f) {
    unsigned u = __float_as_uint(f);
    u = u + 0x7FFFu + ((u >> 16) & 1u);      // RNE
    return (unsigned short)(u >> 16);
}
static __device__ __forceinline__ float bf2f_lo(unsigned u) {
    return __uint_as_float(u << 16);
}
static __device__ __forceinline__ float bf2f_hi(unsigned u) {
    return __uint_as_float(u & 0xFFFF0000u);
}

// async global->LDS, 16B per lane; LDS fills base + lane*16 (wave-uniform base)
static __device__ __forceinline__ void async_copy16(const void* g, void* l) {
    __builtin_amdgcn_global_load_lds(
        (const __attribute__((address_space(1))) unsigned int*)g,
        (__attribute__((address_space(3))) unsigned int*)l, 16, 0, 0);
}

// ---------------- prep: W transposes + edge histogram -----------------------
// cursor (and dhist after it) must be zeroed before this kernel.

__global__ __launch_bounds__(256)
void prep_hist_kernel(const float* __restrict__ W1, unsigned short* __restrict__ W1T,
                      const float* __restrict__ W2, unsigned short* __restrict__ W2T,
                      const float* __restrict__ W3, unsigned short* __restrict__ W3T,
                      const int* __restrict__ ei, int* cursor, int E) {
    int j = blockIdx.x * 256 + threadIdx.x;
    if (j < 256 * 512) {                       // W1 [256,512] -> W1T [512,256]
        int k = j >> 9, n = j & 511;
        W1T[(size_t)n * 256 + k] = f2bf(W1[j]);
        return;
    }
    j -= 256 * 512;
    if (j < 512 * 512) {                       // W2 [512,512] -> W2T [512,512]
        int k = j >> 9, n = j & 511;
        W2T[(size_t)n * 512 + k] = f2bf(W2[j]);
        return;
    }
    j -= 512 * 512;
    if (j < 512 * 128) {                       // W3 [512,128] -> W3T [128,512]
        int k = j >> 7, n = j & 127;
        W3T[(size_t)n * 512 + k] = f2bf(W3[j]);
        return;
    }
    j -= 512 * 128;
    if (j < E) atomicAdd(&cursor[ei[E + j]], 1);   // histogram of dst
}

// ---------------- degree histogram, LDS-privatized (no hot-line atomics) ----
__global__ __launch_bounds__(256)
void hist_kernel(const int* __restrict__ cnt, int* __restrict__ dhist, int N) {
    __shared__ int lh[512];
    for (int k = threadIdx.x; k < 512; k += 256) lh[k] = 0;
    __syncthreads();
    int i = blockIdx.x * 256 + threadIdx.x;
    if (i < N) {
        int v = cnt[i];
        atomicAdd(&lh[v < 511 ? v : 511], 1);
    }
    __syncthreads();
    for (int k = threadIdx.x; k < 512; k += 256)
        if (lh[k]) atomicAdd(&dhist[k], lh[k]);
}

// ---------------- CSR scan (self-loops folded: row_ptr[i]=edge_prefix+i) ----
// Input counts in `cnt`; outputs row_ptr (+N self-loop slots) and leaves
// cnt[i] = row_ptr[i] (write cursor). No global atomics.

__global__ __launch_bounds__(1024)
void scan_bsum_kernel(const int* __restrict__ cnt, int* __restrict__ bsum, int N) {
    __shared__ int wsum[16];
    int tid = threadIdx.x, lane = tid & 63, w = tid >> 6;
    int i = blockIdx.x * 1024 + tid;
    int v = (i < N) ? cnt[i] : 0;
    #pragma unroll
    for (int off = 32; off; off >>= 1) v += __shfl_xor(v, off, 64);
    if (lane == 0) wsum[w] = v;
    __syncthreads();
    if (tid == 0) {
        int t = 0;
        #pragma unroll
        for (int k = 0; k < 16; ++k) t += wsum[k];
        bsum[blockIdx.x] = t;
    }
}

__global__ __launch_bounds__(1024)
void scan_final_kernel(int* __restrict__ cnt, const int* __restrict__ bsum,
                       int* __restrict__ row_ptr, int N, int NB) {
    __shared__ int wsum[16];
    __shared__ int boff_sh;
    int tid = threadIdx.x, lane = tid & 63, w = tid >> 6;
    if (w == 0) {
        int bv = (lane < NB) ? bsum[lane] : 0;
        int bx = bv;
        #pragma unroll
        for (int off = 1; off < 64; off <<= 1) {
            int t = __shfl_up(bx, off, 64);
            if (lane >= off) bx += t;
        }
        if (lane == blockIdx.x) boff_sh = bx - bv;       // exclusive prefix
        if (blockIdx.x == 0 && lane == 63) row_ptr[N] = bx + N;  // +N self-loops
    }
    int i = blockIdx.x * 1024 + tid;
    int v = (i < N) ? cnt[i] : 0;
    int x = v;
    #pragma unroll
    for (int off = 1; off < 64; off <<= 1) {
        int t = __shfl_up(x, off, 64);
        if (lane >= off) x += t;
    }
    if (lane == 63) wsum[w] = x;
    __syncthreads();
    if (w == 0 && lane < 16) {
        int y = wsum[lane];
        #pragma unroll
        for (int off = 1; off < 16; off <<= 1) {
            int t = __shfl_up(y, off, 64);
            if (lane >= off) y += t;
        }
        wsum[lane] = y;
    }
    __syncthreads();
    int woff = (w == 0) ? 0 : wsum[w - 1];
    int ex = boff_sh + woff + x - v + i;     // + i = self-loop slots
    if (i < N) { row_ptr[i] = ex; cnt[i] = ex; }
}

// exclusive prefix over the 512-bin degree histogram (1 block, 512 threads)
__global__ __launch_bounds__(512)
void deg_scan_kernel(const int* __restrict__ dhist, int* __restrict__ dcur) {
    __shared__ int ws[8];
    int tid = threadIdx.x, lane = tid & 63, w = tid >> 6;
    int v = dhist[tid];
    int x = v;
    #pragma unroll
    for (int off = 1; off < 64; off <<= 1) {
        int t = __shfl_up(x, off, 64);
        if (lane >= off) x += t;
    }
    if (lane == 63) ws[w] = x;
    __syncthreads();
    if (w == 0 && lane < 8) {
        int y = ws[lane];
        #pragma unroll
        for (int off = 1; off < 8; off <<= 1) {
            int t = __shfl_up(y, off, 64);
            if (lane >= off) y += t;
        }
        ws[lane] = y;
    }
    __syncthreads();
    int woff = (w == 0) ? 0 : ws[w - 1];
    dcur[tid] = woff + x - v;                // exclusive prefix
}

// degree-sorted ranking: node_order[rank]=node, inv_order[node]=rank,
// sdeg[rank] = edge-degree (input for the second, sorted-space scan)
__global__ __launch_bounds__(256)
void rank_kernel(const int* __restrict__ row_ptr, int* __restrict__ dcur,
                 int* __restrict__ node_order, int* __restrict__ inv_order,
                 int* __restrict__ sdeg, int N) {
    int n = blockIdx.x * 256 + threadIdx.x;
    if (n < N) {
        int d = row_ptr[n + 1] - row_ptr[n] - 1;     // edge-degree
        int pos = atomicAdd(&dcur[d < 511 ? d : 511], 1);
        node_order[pos] = n;
        inv_order[n] = pos;
        sdeg[pos] = d;
    }
}

// edge scatter into SORTED-space csr (cursors = sdeg after 2nd scan) + x cast
__global__ __launch_bounds__(256)
void scatter_xcast_kernel(const int* __restrict__ ei, int* scur,
                          int* __restrict__ csr_src,
                          const int* __restrict__ node_order,
                          const int* __restrict__ inv_order,
                          const float* __restrict__ x,
                          unsigned short* __restrict__ x_bf,
                          int E, int N) {
    int i = blockIdx.x * 256 + threadIdx.x;
    if (i < E) {
        int s = ei[i], d = ei[E + i];
        int pos = atomicAdd(&scur[inv_order[d]], 1);
        csr_src[pos] = inv_order[s];
    } else if (i < E + N) {
        int n = i - E;
        int pos = atomicAdd(&scur[inv_order[n]], 1);
        csr_src[pos] = inv_order[n];     // self loop
    } else if (i < E + N + N * 64) {     // x: [N,256]f32 -> permuted bf16
        int j = i - E - N;
        int ip = j >> 6, c4 = j & 63;    // dst row (sorted space), float4 col
        int node = node_order[ip];
        float4 v = ((const float4*)x)[(size_t)node * 64 + c4];
        ushort4 o;
        o.x = f2bf(v.x); o.y = f2bf(v.y); o.z = f2bf(v.z); o.w = f2bf(v.w);
        ((ushort4*)x_bf)[(size_t)ip * 64 + c4] = o;
    }
}

// ---------------- bf16 MFMA GEMM + fused attention dots ----------------

template<int TM, int TN>
__global__ __launch_bounds__(512)
void mfma_gemm_kernel(const unsigned short* __restrict__ A,
                      const unsigned short* __restrict__ BT,
                      unsigned short* __restrict__ C,
                      const float* __restrict__ att_src,
                      const float* __restrict__ att_dst,
                      float* __restrict__ a_srcO, float* __restrict__ a_dstO,
                      int H, int M, int Nn, int K) {
    constexpr int NH = TN / 128;               // heads per block
    __shared__ unsigned short buf[(TM + TN) * 64];    // 48 KB
    __shared__ float psum[TN / 64][TM];
    __shared__ float pdsum[TN / 64][TM];
    const int tid = threadIdx.x;
    const int m0 = blockIdx.y * TM;
    const int n0 = blockIdx.x * TN;
    const int head_base = blockIdx.x * NH;
    const int lane = tid & 63, wave = tid >> 6;        // wave 0..7
    const int wm = (wave & (TM / 64 - 1)) * 64;
    const int wn = (wave / (TM / 64)) * 64;
    const int quad = lane >> 4, rr = lane & 15;

    const int srow = lane >> 3;                // row within 8-row group
    const int sseg = (lane & 7) ^ srow;        // logical 8-elem seg to fetch
    const unsigned short* gptr[6];
    unsigned short* lptr[6];
    #pragma unroll
    for (int j = 0; j < 6; ++j) {
        int base_row = wave * 48 + j * 8;      // multiple of 8; A/B uniform
        lptr[j] = buf + base_row * 64;
        if (base_row < TM) {
            int gr = min(m0 + base_row + srow, M - 1);
            gptr[j] = A + (size_t)gr * K;
        } else {
            int gr = n0 + (base_row - TM) + srow;
            gptr[j] = BT + (size_t)gr * K;
        }
    }

    floatx4 acc[4][4] = {};

    for (int k0 = 0; k0 < K; k0 += 64) {
        #pragma unroll
        for (int j = 0; j < 6; ++j)
            async_copy16(gptr[j] + k0 + sseg * 8, lptr[j]);
        __syncthreads();

        #pragma unroll
        for (int k32 = 0; k32 < 2; ++k32) {
            short8 af[4], bf[4];
            #pragma unroll
            for (int mi = 0; mi < 4; ++mi) {
                int row = wm + mi * 16 + rr;
                int phys = (k32 * 4 + quad) ^ (rr & 7);
                af[mi] = *(const short8*)(buf + row * 64 + phys * 8);
            }
            #pragma unroll
            for (int ni = 0; ni < 4; ++ni) {
                int row = TM + wn + ni * 16 + rr;
                int phys = (k32 * 4 + quad) ^ (rr & 7);
                bf[ni] = *(const short8*)(buf + row * 64 + phys * 8);
            }
            #pragma unroll
            for (int mi = 0; mi < 4; ++mi)
                #pragma unroll
                for (int ni = 0; ni < 4; ++ni)
                    acc[mi][ni] = __builtin_amdgcn_mfma_f32_16x16x32_bf16(
                        af[mi], bf[ni], acc[mi][ni], 0, 0, 0);
        }
        __syncthreads();
    }

    // ---- h store (bf16), C/D layout: col=lane&15, row=quad*4+reg ----
    #pragma unroll
    for (int mi = 0; mi < 4; ++mi) {
        #pragma unroll
        for (int ni = 0; ni < 4; ++ni) {
            int col = n0 + wn + ni * 16 + rr;
            #pragma unroll
            for (int r = 0; r < 4; ++r) {
                int row = m0 + wm + mi * 16 + quad * 4 + r;
                if (row < M) C[(size_t)row * Nn + col] = f2bf(acc[mi][ni][r]);
            }
        }
    }

    // ---- fused attention dots (per covered head) ----
    float ats[4], atd[4];
    #pragma unroll
    for (int ni = 0; ni < 4; ++ni) {
        int cc = wn + ni * 16;                  // col within block tile
        int h = head_base + (cc >> 7);
        int c = (cc + rr) & 127;                // channel within head
        ats[ni] = att_src[h * 128 + c];
        atd[ni] = att_dst[h * 128 + c];
    }
    const int wg = wn >> 6;                     // wave column group
    #pragma unroll
    for (int mi = 0; mi < 4; ++mi) {
        #pragma unroll
        for (int r = 0; r < 4; ++r) {
            float ps = 0.f, pd = 0.f;
            #pragma unroll
            for (int ni = 0; ni < 4; ++ni) {
                ps += ats[ni] * acc[mi][ni][r];
                pd += atd[ni] * acc[mi][ni][r];
            }
            #pragma unroll
            for (int off = 1; off < 16; off <<= 1) {
                ps += __shfl_xor(ps, off, 64);
                pd += __shfl_xor(pd, off, 64);
            }
            if (rr == 0) {
                int row = wm + mi * 16 + quad * 4 + r;   // local row
                psum[wg][row] = ps;
                pdsum[wg][row] = pd;
            }
        }
    }
    __syncthreads();
    if (tid < NH * TM) {
        int h = tid / TM, r = tid % TM;
        int gr = m0 + r;
        if (gr < M) {
            // [H][N] layout, permuted space (rows already sorted)
            a_srcO[(size_t)(head_base + h) * M + gr] = psum[2 * h][r] + psum[2 * h + 1][r];
            a_dstO[(size_t)(head_base + h) * M + gr] = pdsum[2 * h][r] + pdsum[2 * h + 1][r];
        }
    }
}

// ---------------- agg variant A: XCD-sliced group-per-node (R17) ------------

template<int F, int H, int NSLICE, bool RELU, bool BF16OUT>
__global__ __launch_bounds__(256)
void agg_kernel(const unsigned* __restrict__ hfeat, const float* __restrict__ a_src,
                const float* __restrict__ a_dst, const int* __restrict__ row_ptr_s,
                const int* __restrict__ csr_src, const int* __restrict__ node_order,
                const float* __restrict__ bias, void* __restrict__ out_v, int N) {
    constexpr int RU = F / 2;                // uints per feature row
    constexpr int SU = RU / NSLICE;          // uints per slice (32 -> 128B)
    constexpr int GS = SU / 4;               // lanes per group (8)
    constexpr int GPW = 64 / GS;             // nodes per wave (8)
    constexpr int FS = F / NSLICE;           // feats per slice (64)
    static_assert(GS == 8, "group size must be 8");
    const int lane = threadIdx.x & 63, wave = threadIdx.x >> 6;
    const int s = blockIdx.x % NSLICE;       // FIXED slice -> XCD affinity
    const int g = lane >> 3, l = lane & 7;
    int ni = ((blockIdx.x / NSLICE) * 4 + wave) * GPW + g;   // sorted position
    ni = ni < N ? ni : N - 1;                // dup tail: same bytes, benign
    const int begin = row_ptr_s[ni];
    const int deg = row_ptr_s[ni + 1] - begin;     // >= 1 (self-loop)
    const int h = (s * FS) / (F / H);
    const float adst = a_dst[(size_t)h * N + ni];  // permuted, sequential
    const unsigned* __restrict__ sbase = hfeat + (size_t)s * SU + l * 4;
    const float* __restrict__ asrc_h = a_src + (size_t)h * N;
    const int* __restrict__ crow = csr_src + begin;

    int maxd = deg;                          // max degree across the 8 groups
    #pragma unroll
    for (int off = 8; off < 64; off <<= 1) {
        int t = __shfl_xor(maxd, off, 64);
        maxd = t > maxd ? t : maxd;
    }

    float acc[8] = {};
    float dacc = 0.f;
    uintx4 u0, u1, u2, u3;
    float av0, av1, av2, av3;

#define LOADSLOT(idx, U, AV)                                                  \
    {                                                                         \
        int e_ = (idx) < deg ? (idx) : deg - 1;                               \
        int src_ = __builtin_nontemporal_load(crow + e_);   /* position */    \
        U = *(const uintx4*)(sbase + (size_t)src_ * RU);                      \
        AV = asrc_h[src_];                                                    \
    }

#define CONSUME(idx, U, AV)                                                   \
    {                                                                         \
        float e_ = AV + adst;                                                 \
        e_ = fmaxf(e_, NEG_SLOPE * e_);                                       \
        float ex_ = ((idx) < deg) ? __expf(e_) : 0.f;                         \
        dacc += ex_;                                                          \
        _Pragma("unroll")                                                     \
        for (int q_ = 0; q_ < 4; ++q_) {                                      \
            acc[2 * q_]     += ex_ * bf2f_lo(U[q_]);                          \
            acc[2 * q_ + 1] += ex_ * bf2f_hi(U[q_]);                          \
        }                                                                     \
    }

    LOADSLOT(0, u0, av0);
    LOADSLOT(1, u1, av1);
    LOADSLOT(2, u2, av2);
    LOADSLOT(3, u3, av3);
    int i = 0;
    for (; i + 4 < maxd; i += 4) {
        CONSUME(i,     u0, av0); LOADSLOT(i + 4, u0, av0);
        CONSUME(i + 1, u1, av1); LOADSLOT(i + 5, u1, av1);
        CONSUME(i + 2, u2, av2); LOADSLOT(i + 6, u2, av2);
        CONSUME(i + 3, u3, av3); LOADSLOT(i + 7, u3, av3);
    }
    CONSUME(i,     u0, av0);
    CONSUME(i + 1, u1, av1);
    CONSUME(i + 2, u2, av2);
    CONSUME(i + 3, u3, av3);
#undef LOADSLOT
#undef CONSUME

    float inv = 1.f / dacc;
    const int cb = s * FS + l * 8;           // feature base of this lane
    float v[8];
    #pragma unroll
    for (int j = 0; j < 8; ++j) {
        float t = acc[j] * inv + bias[cb + j];
        v[j] = RELU ? fmaxf(t, 0.f) : t;
    }
    if (BF16OUT) {
        uintx4 pk;
        #pragma unroll
        for (int q = 0; q < 4; ++q)
            pk[q] = (unsigned)f2bf(v[2 * q]) | ((unsigned)f2bf(v[2 * q + 1]) << 16);
        __builtin_nontemporal_store(pk,                       // permuted, seq
            (uintx4*)((unsigned*)out_v + (size_t)ni * RU + s * SU + l * 4));
    } else {
        const int node = node_order[ni];                      // original order
        floatx4 o0 = {v[0], v[1], v[2], v[3]};
        floatx4 o1 = {v[4], v[5], v[6], v[7]};
        float* dst = (float*)out_v + (size_t)node * F + cb;
        __builtin_nontemporal_store(o0, (floatx4*)dst);
        __builtin_nontemporal_store(o1, (floatx4*)(dst + 4));
    }
}

// ---------------- agg variant B: full-row wave-per-node (R11, sorted space) -
// One WAVE per dst position. Single pass exp (no max subtraction, fp32-safe).
// Depth-4 pipelined full-row gathers (16B/lane); scalarized CSR chain.
// a_src/a_dst in [H][N] layout; everything in sorted space.

template<int F, int H, bool RELU, bool BF16OUT>
__global__ __launch_bounds__(256)
void agg_full_kernel(const unsigned* __restrict__ hfeat, const float* __restrict__ a_src,
                     const float* __restrict__ a_dst, const int* __restrict__ row_ptr_s,
                     const int* __restrict__ csr_src, const float* __restrict__ bias,
                     void* __restrict__ out_v, int N) {
    constexpr int UPL = F / 128;             // uints per lane: 4 or 1
    constexpr int RU = F / 2;                // uints per row
    const int wave = threadIdx.x >> 6, lane = threadIdx.x & 63;
    const int n = blockIdx.x * 4 + wave;     // sorted position
    if (n >= N) return;
    const int begin = __builtin_amdgcn_readfirstlane(row_ptr_s[n]);
    const int deg = __builtin_amdgcn_readfirstlane(row_ptr_s[n + 1]) - begin;
    const int myh = (2 * UPL * lane) / 128;
    const float adst = a_dst[(size_t)myh * N + n];

    float acc[2 * UPL];
    #pragma unroll
    for (int j = 0; j < 2 * UPL; ++j) acc[j] = 0.f;
    float dacc = 0.f;

    unsigned u0[UPL], u1[UPL], u2[UPL], u3[UPL];
    float av0 = 0.f, av1 = 0.f, av2 = 0.f, av3 = 0.f;

#define LOADSLOT(idx, U, AV)                                              \
    {                                                                     \
        int s_ = __builtin_amdgcn_readfirstlane(csr_src[begin + (idx)]);  \
        if (UPL == 4) {                                                   \
            uint4 t_ = ((const uint4*)(hfeat + (size_t)s_ * RU))[lane];   \
            U[0] = t_.x; U[1] = t_.y; U[2] = t_.z; U[3] = t_.w;           \
        } else {                                                          \
            U[0] = hfeat[(size_t)s_ * RU + lane];                         \
        }                                                                 \
        AV = a_src[(size_t)myh * N + s_];                                 \
    }

#define CONSUME(U, AV)                                                    \
    {                                                                     \
        float e_ = AV + adst;                                             \
        e_ = e_ > 0.f ? e_ : NEG_SLOPE * e_;                              \
        float ex_ = __expf(e_);                                           \
        dacc += ex_;                                                      \
        _Pragma("unroll")                                                 \
        for (int q_ = 0; q_ < UPL; ++q_) {                                \
            acc[2 * q_]     += ex_ * bf2f_lo(U[q_]);                      \
            acc[2 * q_ + 1] += ex_ * bf2f_hi(U[q_]);                      \
        }                                                                 \
    }

    LOADSLOT(0, u0, av0);
    if (deg > 1) LOADSLOT(1, u1, av1);
    if (deg > 2) LOADSLOT(2, u2, av2);
    if (deg > 3) LOADSLOT(3, u3, av3);
    int i = 0;
    for (; i + 8 <= deg; i += 4) {
        CONSUME(u0, av0); LOADSLOT(i + 4, u0, av0);
        CONSUME(u1, av1); LOADSLOT(i + 5, u1, av1);
        CONSUME(u2, av2); LOADSLOT(i + 6, u2, av2);
        CONSUME(u3, av3); LOADSLOT(i + 7, u3, av3);
    }
    int rem = deg - i;                       // 1..7
    CONSUME(u0, av0); if (rem > 4) LOADSLOT(i + 4, u0, av0);
    if (rem > 1) { CONSUME(u1, av1); if (rem > 5) LOADSLOT(i + 5, u1, av1); }
    if (rem > 2) { CONSUME(u2, av2); if (rem > 6) LOADSLOT(i + 6, u2, av2); }
    if (rem > 3) CONSUME(u3, av3);
    if (rem > 4) CONSUME(u0, av0);
    if (rem > 5) CONSUME(u1, av1);
    if (rem > 6) CONSUME(u2, av2);
#undef LOADSLOT
#undef CONSUME

    float inv = 1.f / dacc;
    const int cb = 2 * UPL * lane;
    if (BF16OUT) {
        unsigned pk[UPL];
        #pragma unroll
        for (int q = 0; q < UPL; ++q) {
            float v0 = acc[2 * q] * inv + bias[cb + 2 * q];
            float v1 = acc[2 * q + 1] * inv + bias[cb + 2 * q + 1];
            if (RELU) { v0 = fmaxf(v0, 0.f); v1 = fmaxf(v1, 0.f); }
            pk[q] = (unsigned)f2bf(v0) | ((unsigned)f2bf(v1) << 16);
        }
        if (UPL == 4) {
            uint4 t; t.x = pk[0]; t.y = pk[1]; t.z = pk[2]; t.w = pk[3];
            ((uint4*)((unsigned*)out_v + (size_t)n * RU))[lane] = t;
        } else {
            ((unsigned*)out_v)[(size_t)n * RU + lane] = pk[0];
        }
    } else {
        #pragma unroll
        for (int q = 0; q < UPL; ++q) {
            float v0 = acc[2 * q] * inv + bias[cb + 2 * q];
            float v1 = acc[2 * q + 1] * inv + bias[cb + 2 * q + 1];
            if (RELU) { v0 = fmaxf(v0, 0.f); v1 = fmaxf(v1, 0.f); }
            float2 o; o.x = v0; o.y = v1;
            ((float2*)((float*)out_v + (size_t)n * F))[UPL * lane + q] = o;
        }
    }
}

// ---------------- host launch ----------------

extern "C" void kernel_launch(void* const* d_in, const int* in_sizes, int n_in,
                              void* d_out, int out_size, void* d_ws, size_t ws_size,
                              hipStream_t stream) {
    const float* x        = (const float*)d_in[0];
    const int*   ei       = (const int*)  d_in[1];
    const float* W1       = (const float*)d_in[2];
    const float* att_src1 = (const float*)d_in[3];
    const float* att_dst1 = (const float*)d_in[4];
    const float* b1       = (const float*)d_in[5];
    const float* W2       = (const float*)d_in[6];
    const float* att_src2 = (const float*)d_in[7];
    const float* att_dst2 = (const float*)d_in[8];
    const float* b2       = (const float*)d_in[9];
    const float* W3       = (const float*)d_in[10];
    const float* att_src3 = (const float*)d_in[11];
    const float* att_dst3 = (const float*)d_in[12];
    const float* b3       = (const float*)d_in[13];

    const int IN_FEATS = 256;
    const int N = in_sizes[0] / IN_FEATS;   // 30000
    const int E = in_sizes[1] / 2;          // 480000
    const int ET = E + N;
    const int NB = (N + 1023) / 1024;       // scan blocks (30)

    // workspace layout
    char* p = (char*)d_ws;
    unsigned short* h_bf    = (unsigned short*)p; p += (size_t)N * 512 * sizeof(unsigned short);
    unsigned short* act_bf  = (unsigned short*)p; p += (size_t)N * 512 * sizeof(unsigned short);
    unsigned short* x_bf    = (unsigned short*)p; p += (size_t)N * 256 * sizeof(unsigned short);
    float*          a_src   = (float*)p;          p += (size_t)N * 4 * sizeof(float);
    float*          a_dst   = (float*)p;          p += (size_t)N * 4 * sizeof(float);
    unsigned short* W1T     = (unsigned short*)p; p += (size_t)512 * 256 * sizeof(unsigned short);
    unsigned short* W2T     = (unsigned short*)p; p += (size_t)512 * 512 * sizeof(unsigned short);
    unsigned short* W3T     = (unsigned short*)p; p += (size_t)128 * 512 * sizeof(unsigned short);
    int*            row_ptr = (int*)p;            p += ((size_t)N + 16) * sizeof(int);   // original space
    int*            row_ptr_s = (int*)p;          p += ((size_t)N + 16) * sizeof(int);   // sorted space
    int*            cursor  = (int*)p;            p += (size_t)N * sizeof(int);
    int*            dhist   = (int*)p;            p += 512 * sizeof(int);
    int*            dcur    = (int*)p;            p += 512 * sizeof(int);
    int*            node_order = (int*)p;         p += (size_t)N * sizeof(int);
    int*            inv_order  = (int*)p;         p += (size_t)N * sizeof(int);
    int*            sdeg    = (int*)p;            p += (size_t)N * sizeof(int);
    int*            bsum    = (int*)p;            p += 64 * sizeof(int);
    int*            csr_src = (int*)p;            p += (size_t)ET * sizeof(int);

    // ---- prep: W transposes + hist; CSR build (orig) -> rank -> CSR (sorted)
    hipMemsetAsync(cursor, 0, ((size_t)N + 512) * sizeof(int), stream); // cursor+dhist
    {
        int total = 256 * 512 + 512 * 512 + 512 * 128 + E;
        prep_hist_kernel<<<(total + 255) / 256, 256, 0, stream>>>(
            W1, W1T, W2, W2T, W3, W3T, ei, cursor, E);
    }
    hist_kernel<<<(N + 255) / 256, 256, 0, stream>>>(cursor, dhist, N);
    scan_bsum_kernel<<<NB, 1024, 0, stream>>>(cursor, bsum, N);
    scan_final_kernel<<<NB, 1024, 0, stream>>>(cursor, bsum, row_ptr, N, NB);
    deg_scan_kernel<<<1, 512, 0, stream>>>(dhist, dcur);
    rank_kernel<<<(N + 255) / 256, 256, 0, stream>>>(row_ptr, dcur, node_order, inv_order, sdeg, N);
    // second scan: sorted-space row_ptr_s + write cursors (sdeg -> cursors)
    scan_bsum_kernel<<<NB, 1024, 0, stream>>>(sdeg, bsum, N);
    scan_final_kernel<<<NB, 1024, 0, stream>>>(sdeg, bsum, row_ptr_s, N, NB);
    {
        int total = E + N + N * 64;          // edges + self-loops + x float4s
        scatter_xcast_kernel<<<(total + 255) / 256, 256, 0, stream>>>(
            ei, sdeg, csr_src, node_order, inv_order, x, x_bf, E, N);
    }

    const int MB128 = (N + 127) / 128;      // 235
    const int MB256 = (N + 255) / 256;      // 118
    const int NC32 = (N + 31) / 32;         // node chunks (sliced agg)
    const int NB4 = (N + 3) / 4;            // 4 waves/block (full agg)

    // ---- Layer 1: sliced agg (variant A) ----
    mfma_gemm_kernel<128, 256><<<dim3(2, MB128), 512, 0, stream>>>(x_bf, W1T, h_bf, att_src1, att_dst1, a_src, a_dst, 4, N, 512, 256);
    agg_kernel<512, 4, 8, true, true><<<8 * NC32, 256, 0, stream>>>((const unsigned*)h_bf, a_src, a_dst, row_ptr_s, csr_src, node_order, b1, act_bf, N);

    // ---- Layer 2: full-row agg (variant B, R11-proven) ----
    mfma_gemm_kernel<128, 256><<<dim3(2, MB128), 512, 0, stream>>>(act_bf, W2T, h_bf, att_src2, att_dst2, a_src, a_dst, 4, N, 512, 512);
    agg_full_kernel<512, 4, true, true><<<NB4, 256, 0, stream>>>((const unsigned*)h_bf, a_src, a_dst, row_ptr_s, csr_src, b2, act_bf, N);

    // ---- Layer 3: 512 -> 1x128, fp32 out (original order), no relu ----
    mfma_gemm_kernel<256, 128><<<dim3(1, MB256), 512, 0, stream>>>(act_bf, W3T, h_bf, att_src3, att_dst3, a_src, a_dst, 1, N, 128, 512);
    agg_kernel<128, 1, 2, false, false><<<2 * NC32, 256, 0, stream>>>((const unsigned*)h_bf, a_src, a_dst, row_ptr_s, csr_src, node_order, b3, d_out, N);
}

// Round 9
// 481.070 us; speedup vs baseline: 1.5743x; 1.0255x over previous
//
#include <hip/hip_runtime.h>

// ---------------------------------------------------------------------------
// DistributionShiftGAT: 3-layer GAT on MI355X (gfx950).
// R19 (resubmit; R8's bench was lost to a GPU-acquisition timeout).
//      Sliced agg inner loop made memory-shaped. R18 A/B: sliced = 93us
//      (FETCH 50MB, VALU 37% -> stall-bound), full-row <93us. Fixes:
//      (1) per-(edge,head) softmax weights precomputed after each GEMM
//          (w[h][e]=exp(leaky(asrc+adst)), 8.2MB seq); sliced loop is now
//          csr(seq ushort) + w(seq f32) + 128B gather + 8 FMA — the 8x
//          redundant quarter-rate v_exp_f32 and random a_src gather are gone.
//      (2) csr as ushort (pos<65536): halves csr traffic.
//      (3) NT dropped from csr/w loads (NT defeated L1 reuse of the csr
//          line re-read ~16x per group; NT only on output stores now).
//      Layer 2 keeps full-row variant B as in-run control.
// ---------------------------------------------------------------------------

#define NEG_SLOPE 0.2f

typedef __attribute__((ext_vector_type(8))) short short8;
typedef __attribute__((ext_vector_type(4))) float floatx4;
typedef __attribute__((ext_vector_type(4))) unsigned uintx4;

static __device__ __forceinline__ unsigned short f2bf(float f) {
    unsigned u = __float_as_uint(f);
    u = u + 0x7FFFu + ((u >> 16) & 1u);      // RNE
    return (unsigned short)(u >> 16);
}
static __device__ __forceinline__ float bf2f_lo(unsigned u) {
    return __uint_as_float(u << 16);
}
static __device__ __forceinline__ float bf2f_hi(unsigned u) {
    return __uint_as_float(u & 0xFFFF0000u);
}

// async global->LDS, 16B per lane; LDS fills base + lane*16 (wave-uniform base)
static __device__ __forceinline__ void async_copy16(const void* g, void* l) {
    __builtin_amdgcn_global_load_lds(
        (const __attribute__((address_space(1))) unsigned int*)g,
        (__attribute__((address_space(3))) unsigned int*)l, 16, 0, 0);
}

// ---------------- prep: W transposes + edge histogram -----------------------
// cursor (and dhist after it) must be zeroed before this kernel.

__global__ __launch_bounds__(256)
void prep_hist_kernel(const float* __restrict__ W1, unsigned short* __restrict__ W1T,
                      const float* __restrict__ W2, unsigned short* __restrict__ W2T,
                      const float* __restrict__ W3, unsigned short* __restrict__ W3T,
                      const int* __restrict__ ei, int* cursor, int E) {
    int j = blockIdx.x * 256 + threadIdx.x;
    if (j < 256 * 512) {                       // W1 [256,512] -> W1T [512,256]
        int k = j >> 9, n = j & 511;
        W1T[(size_t)n * 256 + k] = f2bf(W1[j]);
        return;
    }
    j -= 256 * 512;
    if (j < 512 * 512) {                       // W2 [512,512] -> W2T [512,512]
        int k = j >> 9, n = j & 511;
        W2T[(size_t)n * 512 + k] = f2bf(W2[j]);
        return;
    }
    j -= 512 * 512;
    if (j < 512 * 128) {                       // W3 [512,128] -> W3T [128,512]
        int k = j >> 7, n = j & 127;
        W3T[(size_t)n * 512 + k] = f2bf(W3[j]);
        return;
    }
    j -= 512 * 128;
    if (j < E) atomicAdd(&cursor[ei[E + j]], 1);   // histogram of dst
}

// ---------------- degree histogram, LDS-privatized (no hot-line atomics) ----
__global__ __launch_bounds__(256)
void hist_kernel(const int* __restrict__ cnt, int* __restrict__ dhist, int N) {
    __shared__ int lh[512];
    for (int k = threadIdx.x; k < 512; k += 256) lh[k] = 0;
    __syncthreads();
    int i = blockIdx.x * 256 + threadIdx.x;
    if (i < N) {
        int v = cnt[i];
        atomicAdd(&lh[v < 511 ? v : 511], 1);
    }
    __syncthreads();
    for (int k = threadIdx.x; k < 512; k += 256)
        if (lh[k]) atomicAdd(&dhist[k], lh[k]);
}

// ---------------- CSR scan (self-loops folded: row_ptr[i]=edge_prefix+i) ----

__global__ __launch_bounds__(1024)
void scan_bsum_kernel(const int* __restrict__ cnt, int* __restrict__ bsum, int N) {
    __shared__ int wsum[16];
    int tid = threadIdx.x, lane = tid & 63, w = tid >> 6;
    int i = blockIdx.x * 1024 + tid;
    int v = (i < N) ? cnt[i] : 0;
    #pragma unroll
    for (int off = 32; off; off >>= 1) v += __shfl_xor(v, off, 64);
    if (lane == 0) wsum[w] = v;
    __syncthreads();
    if (tid == 0) {
        int t = 0;
        #pragma unroll
        for (int k = 0; k < 16; ++k) t += wsum[k];
        bsum[blockIdx.x] = t;
    }
}

__global__ __launch_bounds__(1024)
void scan_final_kernel(int* __restrict__ cnt, const int* __restrict__ bsum,
                       int* __restrict__ row_ptr, int N, int NB) {
    __shared__ int wsum[16];
    __shared__ int boff_sh;
    int tid = threadIdx.x, lane = tid & 63, w = tid >> 6;
    if (w == 0) {
        int bv = (lane < NB) ? bsum[lane] : 0;
        int bx = bv;
        #pragma unroll
        for (int off = 1; off < 64; off <<= 1) {
            int t = __shfl_up(bx, off, 64);
            if (lane >= off) bx += t;
        }
        if (lane == blockIdx.x) boff_sh = bx - bv;       // exclusive prefix
        if (blockIdx.x == 0 && lane == 63) row_ptr[N] = bx + N;  // +N self-loops
    }
    int i = blockIdx.x * 1024 + tid;
    int v = (i < N) ? cnt[i] : 0;
    int x = v;
    #pragma unroll
    for (int off = 1; off < 64; off <<= 1) {
        int t = __shfl_up(x, off, 64);
        if (lane >= off) x += t;
    }
    if (lane == 63) wsum[w] = x;
    __syncthreads();
    if (w == 0 && lane < 16) {
        int y = wsum[lane];
        #pragma unroll
        for (int off = 1; off < 16; off <<= 1) {
            int t = __shfl_up(y, off, 64);
            if (lane >= off) y += t;
        }
        wsum[lane] = y;
    }
    __syncthreads();
    int woff = (w == 0) ? 0 : wsum[w - 1];
    int ex = boff_sh + woff + x - v + i;     // + i = self-loop slots
    if (i < N) { row_ptr[i] = ex; cnt[i] = ex; }
}

// exclusive prefix over the 512-bin degree histogram (1 block, 512 threads)
__global__ __launch_bounds__(512)
void deg_scan_kernel(const int* __restrict__ dhist, int* __restrict__ dcur) {
    __shared__ int ws[8];
    int tid = threadIdx.x, lane = tid & 63, w = tid >> 6;
    int v = dhist[tid];
    int x = v;
    #pragma unroll
    for (int off = 1; off < 64; off <<= 1) {
        int t = __shfl_up(x, off, 64);
        if (lane >= off) x += t;
    }
    if (lane == 63) ws[w] = x;
    __syncthreads();
    if (w == 0 && lane < 8) {
        int y = ws[lane];
        #pragma unroll
        for (int off = 1; off < 8; off <<= 1) {
            int t = __shfl_up(y, off, 64);
            if (lane >= off) y += t;
        }
        ws[lane] = y;
    }
    __syncthreads();
    int woff = (w == 0) ? 0 : ws[w - 1];
    dcur[tid] = woff + x - v;                // exclusive prefix
}

// degree-sorted ranking: node_order[rank]=node, inv_order[node]=rank,
// sdeg[rank] = edge-degree (input for the second, sorted-space scan)
__global__ __launch_bounds__(256)
void rank_kernel(const int* __restrict__ row_ptr, int* __restrict__ dcur,
                 int* __restrict__ node_order, int* __restrict__ inv_order,
                 int* __restrict__ sdeg, int N) {
    int n = blockIdx.x * 256 + threadIdx.x;
    if (n < N) {
        int d = row_ptr[n + 1] - row_ptr[n] - 1;     // edge-degree
        int pos = atomicAdd(&dcur[d < 511 ? d : 511], 1);
        node_order[pos] = n;
        inv_order[n] = pos;
        sdeg[pos] = d;
    }
}

// edge scatter into SORTED-space csr (ushort src-pos + ushort dst-pos) + x cast
__global__ __launch_bounds__(256)
void scatter_xcast_kernel(const int* __restrict__ ei, int* scur,
                          unsigned short* __restrict__ csr_src,
                          unsigned short* __restrict__ csr_dpos,
                          const int* __restrict__ node_order,
                          const int* __restrict__ inv_order,
                          const float* __restrict__ x,
                          unsigned short* __restrict__ x_bf,
                          int E, int N) {
    int i = blockIdx.x * 256 + threadIdx.x;
    if (i < E) {
        int s = ei[i], d = ei[E + i];
        int dp = inv_order[d];
        int pos = atomicAdd(&scur[dp], 1);
        csr_src[pos] = (unsigned short)inv_order[s];
        csr_dpos[pos] = (unsigned short)dp;
    } else if (i < E + N) {
        int n = i - E;
        int np = inv_order[n];
        int pos = atomicAdd(&scur[np], 1);
        csr_src[pos] = (unsigned short)np;   // self loop
        csr_dpos[pos] = (unsigned short)np;
    } else if (i < E + N + N * 64) {     // x: [N,256]f32 -> permuted bf16
        int j = i - E - N;
        int ip = j >> 6, c4 = j & 63;    // dst row (sorted space), float4 col
        int node = node_order[ip];
        float4 v = ((const float4*)x)[(size_t)node * 64 + c4];
        ushort4 o;
        o.x = f2bf(v.x); o.y = f2bf(v.y); o.z = f2bf(v.z); o.w = f2bf(v.w);
        ((ushort4*)x_bf)[(size_t)ip * 64 + c4] = o;
    }
}

// ---------------- per-(edge,head) softmax weights ---------------------------
// w[h][e] = exp(leaky_relu(a_src[h][src(e)] + a_dst[h][dpos(e)])).
// a_src/a_dst: 480KB total, L2-resident on every XCD. Sequential csr reads,
// sequential w writes. Single-pass exp (no max subtraction; logits O(1)).

template<int H>
__global__ __launch_bounds__(256)
void weight_kernel(const unsigned short* __restrict__ csr_src,
                   const unsigned short* __restrict__ csr_dpos,
                   const float* __restrict__ a_src, const float* __restrict__ a_dst,
                   float* __restrict__ w, int ET, int N) {
    int e = blockIdx.x * 256 + threadIdx.x;
    if (e >= ET) return;
    int s = csr_src[e], d = csr_dpos[e];
    #pragma unroll
    for (int h = 0; h < H; ++h) {
        float v = a_src[(size_t)h * N + s] + a_dst[(size_t)h * N + d];
        v = fmaxf(v, NEG_SLOPE * v);
        w[(size_t)h * ET + e] = __expf(v);
    }
}

// ---------------- bf16 MFMA GEMM + fused attention dots ----------------

template<int TM, int TN>
__global__ __launch_bounds__(512)
void mfma_gemm_kernel(const unsigned short* __restrict__ A,
                      const unsigned short* __restrict__ BT,
                      unsigned short* __restrict__ C,
                      const float* __restrict__ att_src,
                      const float* __restrict__ att_dst,
                      float* __restrict__ a_srcO, float* __restrict__ a_dstO,
                      int H, int M, int Nn, int K) {
    constexpr int NH = TN / 128;               // heads per block
    __shared__ unsigned short buf[(TM + TN) * 64];    // 48 KB
    __shared__ float psum[TN / 64][TM];
    __shared__ float pdsum[TN / 64][TM];
    const int tid = threadIdx.x;
    const int m0 = blockIdx.y * TM;
    const int n0 = blockIdx.x * TN;
    const int head_base = blockIdx.x * NH;
    const int lane = tid & 63, wave = tid >> 6;        // wave 0..7
    const int wm = (wave & (TM / 64 - 1)) * 64;
    const int wn = (wave / (TM / 64)) * 64;
    const int quad = lane >> 4, rr = lane & 15;

    const int srow = lane >> 3;                // row within 8-row group
    const int sseg = (lane & 7) ^ srow;        // logical 8-elem seg to fetch
    const unsigned short* gptr[6];
    unsigned short* lptr[6];
    #pragma unroll
    for (int j = 0; j < 6; ++j) {
        int base_row = wave * 48 + j * 8;      // multiple of 8; A/B uniform
        lptr[j] = buf + base_row * 64;
        if (base_row < TM) {
            int gr = min(m0 + base_row + srow, M - 1);
            gptr[j] = A + (size_t)gr * K;
        } else {
            int gr = n0 + (base_row - TM) + srow;
            gptr[j] = BT + (size_t)gr * K;
        }
    }

    floatx4 acc[4][4] = {};

    for (int k0 = 0; k0 < K; k0 += 64) {
        #pragma unroll
        for (int j = 0; j < 6; ++j)
            async_copy16(gptr[j] + k0 + sseg * 8, lptr[j]);
        __syncthreads();

        #pragma unroll
        for (int k32 = 0; k32 < 2; ++k32) {
            short8 af[4], bf[4];
            #pragma unroll
            for (int mi = 0; mi < 4; ++mi) {
                int row = wm + mi * 16 + rr;
                int phys = (k32 * 4 + quad) ^ (rr & 7);
                af[mi] = *(const short8*)(buf + row * 64 + phys * 8);
            }
            #pragma unroll
            for (int ni = 0; ni < 4; ++ni) {
                int row = TM + wn + ni * 16 + rr;
                int phys = (k32 * 4 + quad) ^ (rr & 7);
                bf[ni] = *(const short8*)(buf + row * 64 + phys * 8);
            }
            #pragma unroll
            for (int mi = 0; mi < 4; ++mi)
                #pragma unroll
                for (int ni = 0; ni < 4; ++ni)
                    acc[mi][ni] = __builtin_amdgcn_mfma_f32_16x16x32_bf16(
                        af[mi], bf[ni], acc[mi][ni], 0, 0, 0);
        }
        __syncthreads();
    }

    // ---- h store (bf16), C/D layout: col=lane&15, row=quad*4+reg ----
    #pragma unroll
    for (int mi = 0; mi < 4; ++mi) {
        #pragma unroll
        for (int ni = 0; ni < 4; ++ni) {
            int col = n0 + wn + ni * 16 + rr;
            #pragma unroll
            for (int r = 0; r < 4; ++r) {
                int row = m0 + wm + mi * 16 + quad * 4 + r;
                if (row < M) C[(size_t)row * Nn + col] = f2bf(acc[mi][ni][r]);
            }
        }
    }

    // ---- fused attention dots (per covered head) ----
    float ats[4], atd[4];
    #pragma unroll
    for (int ni = 0; ni < 4; ++ni) {
        int cc = wn + ni * 16;                  // col within block tile
        int h = head_base + (cc >> 7);
        int c = (cc + rr) & 127;                // channel within head
        ats[ni] = att_src[h * 128 + c];
        atd[ni] = att_dst[h * 128 + c];
    }
    const int wg = wn >> 6;                     // wave column group
    #pragma unroll
    for (int mi = 0; mi < 4; ++mi) {
        #pragma unroll
        for (int r = 0; r < 4; ++r) {
            float ps = 0.f, pd = 0.f;
            #pragma unroll
            for (int ni = 0; ni < 4; ++ni) {
                ps += ats[ni] * acc[mi][ni][r];
                pd += atd[ni] * acc[mi][ni][r];
            }
            #pragma unroll
            for (int off = 1; off < 16; off <<= 1) {
                ps += __shfl_xor(ps, off, 64);
                pd += __shfl_xor(pd, off, 64);
            }
            if (rr == 0) {
                int row = wm + mi * 16 + quad * 4 + r;   // local row
                psum[wg][row] = ps;
                pdsum[wg][row] = pd;
            }
        }
    }
    __syncthreads();
    if (tid < NH * TM) {
        int h = tid / TM, r = tid % TM;
        int gr = m0 + r;
        if (gr < M) {
            // [H][N] layout, permuted space (rows already sorted)
            a_srcO[(size_t)(head_base + h) * M + gr] = psum[2 * h][r] + psum[2 * h + 1][r];
            a_dstO[(size_t)(head_base + h) * M + gr] = pdsum[2 * h][r] + pdsum[2 * h + 1][r];
        }
    }
}

// ---------------- agg variant A': XCD-sliced, precomputed weights -----------
// 8-lane group owns one node's 128B slice; inner loop = csr(seq ushort) +
// w(seq f32) + 128B L2-resident gather + 8 FMA + 1 add. No exp, no a_src.

template<int F, int H, int NSLICE, bool RELU, bool BF16OUT>
__global__ __launch_bounds__(256)
void agg_kernel(const unsigned* __restrict__ hfeat, const float* __restrict__ w,
                const int* __restrict__ row_ptr_s,
                const unsigned short* __restrict__ csr_src,
                const int* __restrict__ node_order,
                const float* __restrict__ bias, void* __restrict__ out_v,
                int ET, int N) {
    constexpr int RU = F / 2;                // uints per feature row
    constexpr int SU = RU / NSLICE;          // uints per slice (32 -> 128B)
    constexpr int GS = SU / 4;               // lanes per group (8)
    constexpr int GPW = 64 / GS;             // nodes per wave (8)
    constexpr int FS = F / NSLICE;           // feats per slice (64)
    static_assert(GS == 8, "group size must be 8");
    const int lane = threadIdx.x & 63, wave = threadIdx.x >> 6;
    const int s = blockIdx.x % NSLICE;       // FIXED slice -> XCD affinity
    const int g = lane >> 3, l = lane & 7;
    int ni = ((blockIdx.x / NSLICE) * 4 + wave) * GPW + g;   // sorted position
    ni = ni < N ? ni : N - 1;                // dup tail: same bytes, benign
    const int begin = row_ptr_s[ni];
    const int deg = row_ptr_s[ni + 1] - begin;     // >= 1 (self-loop)
    const int h = (s * FS) / (F / H);
    const unsigned* __restrict__ sbase = hfeat + (size_t)s * SU + l * 4;
    const unsigned short* __restrict__ crow = csr_src + begin;
    const float* __restrict__ wrow = w + (size_t)h * ET + begin;

    int maxd = deg;                          // max degree across the 8 groups
    #pragma unroll
    for (int off = 8; off < 64; off <<= 1) {
        int t = __shfl_xor(maxd, off, 64);
        maxd = t > maxd ? t : maxd;
    }

    float acc[8] = {};
    float dacc = 0.f;
    uintx4 u0, u1, u2, u3;
    float wv0, wv1, wv2, wv3;

#define LOADSLOT(idx, U, WV)                                                  \
    {                                                                         \
        int e_ = (idx) < deg ? (idx) : deg - 1;                               \
        int src_ = crow[e_];                                                  \
        U = *(const uintx4*)(sbase + (size_t)src_ * RU);                      \
        WV = ((idx) < deg) ? wrow[e_] : 0.f;                                  \
    }

#define CONSUME(U, WV)                                                        \
    {                                                                         \
        dacc += WV;                                                           \
        _Pragma("unroll")                                                     \
        for (int q_ = 0; q_ < 4; ++q_) {                                      \
            acc[2 * q_]     += WV * bf2f_lo(U[q_]);                           \
            acc[2 * q_ + 1] += WV * bf2f_hi(U[q_]);                           \
        }                                                                     \
    }

    LOADSLOT(0, u0, wv0);
    LOADSLOT(1, u1, wv1);
    LOADSLOT(2, u2, wv2);
    LOADSLOT(3, u3, wv3);
    int i = 0;
    for (; i + 4 < maxd; i += 4) {
        CONSUME(u0, wv0); LOADSLOT(i + 4, u0, wv0);
        CONSUME(u1, wv1); LOADSLOT(i + 5, u1, wv1);
        CONSUME(u2, wv2); LOADSLOT(i + 6, u2, wv2);
        CONSUME(u3, wv3); LOADSLOT(i + 7, u3, wv3);
    }
    CONSUME(u0, wv0);
    CONSUME(u1, wv1);
    CONSUME(u2, wv2);
    CONSUME(u3, wv3);
#undef LOADSLOT
#undef CONSUME

    float inv = 1.f / dacc;
    const int cb = s * FS + l * 8;           // feature base of this lane
    float v[8];
    #pragma unroll
    for (int j = 0; j < 8; ++j) {
        float t = acc[j] * inv + bias[cb + j];
        v[j] = RELU ? fmaxf(t, 0.f) : t;
    }
    if (BF16OUT) {
        uintx4 pk;
        #pragma unroll
        for (int q = 0; q < 4; ++q)
            pk[q] = (unsigned)f2bf(v[2 * q]) | ((unsigned)f2bf(v[2 * q + 1]) << 16);
        __builtin_nontemporal_store(pk,                       // permuted, seq
            (uintx4*)((unsigned*)out_v + (size_t)ni * RU + s * SU + l * 4));
    } else {
        const int node = node_order[ni];                      // original order
        floatx4 o0 = {v[0], v[1], v[2], v[3]};
        floatx4 o1 = {v[4], v[5], v[6], v[7]};
        float* dst = (float*)out_v + (size_t)node * F + cb;
        __builtin_nontemporal_store(o0, (floatx4*)dst);
        __builtin_nontemporal_store(o1, (floatx4*)(dst + 4));
    }
}

// ---------------- agg variant B: full-row wave-per-node (control) -----------

template<int F, int H, bool RELU, bool BF16OUT>
__global__ __launch_bounds__(256)
void agg_full_kernel(const unsigned* __restrict__ hfeat, const float* __restrict__ a_src,
                     const float* __restrict__ a_dst, const int* __restrict__ row_ptr_s,
                     const unsigned short* __restrict__ csr_src,
                     const float* __restrict__ bias,
                     void* __restrict__ out_v, int N) {
    constexpr int UPL = F / 128;             // uints per lane: 4 or 1
    constexpr int RU = F / 2;                // uints per row
    const int wave = threadIdx.x >> 6, lane = threadIdx.x & 63;
    const int n = blockIdx.x * 4 + wave;     // sorted position
    if (n >= N) return;
    const int begin = __builtin_amdgcn_readfirstlane(row_ptr_s[n]);
    const int deg = __builtin_amdgcn_readfirstlane(row_ptr_s[n + 1]) - begin;
    const int myh = (2 * UPL * lane) / 128;
    const float adst = a_dst[(size_t)myh * N + n];

    float acc[2 * UPL];
    #pragma unroll
    for (int j = 0; j < 2 * UPL; ++j) acc[j] = 0.f;
    float dacc = 0.f;

    unsigned u0[UPL], u1[UPL], u2[UPL], u3[UPL];
    float av0 = 0.f, av1 = 0.f, av2 = 0.f, av3 = 0.f;

#define LOADSLOT(idx, U, AV)                                              \
    {                                                                     \
        int s_ = __builtin_amdgcn_readfirstlane((int)csr_src[begin + (idx)]); \
        if (UPL == 4) {                                                   \
            uint4 t_ = ((const uint4*)(hfeat + (size_t)s_ * RU))[lane];   \
            U[0] = t_.x; U[1] = t_.y; U[2] = t_.z; U[3] = t_.w;           \
        } else {                                                          \
            U[0] = hfeat[(size_t)s_ * RU + lane];                         \
        }                                                                 \
        AV = a_src[(size_t)myh * N + s_];                                 \
    }

#define CONSUME(U, AV)                                                    \
    {                                                                     \
        float e_ = AV + adst;                                             \
        e_ = e_ > 0.f ? e_ : NEG_SLOPE * e_;                              \
        float ex_ = __expf(e_);                                           \
        dacc += ex_;                                                      \
        _Pragma("unroll")                                                 \
        for (int q_ = 0; q_ < UPL; ++q_) {                                \
            acc[2 * q_]     += ex_ * bf2f_lo(U[q_]);                      \
            acc[2 * q_ + 1] += ex_ * bf2f_hi(U[q_]);                      \
        }                                                                 \
    }

    LOADSLOT(0, u0, av0);
    if (deg > 1) LOADSLOT(1, u1, av1);
    if (deg > 2) LOADSLOT(2, u2, av2);
    if (deg > 3) LOADSLOT(3, u3, av3);
    int i = 0;
    for (; i + 8 <= deg; i += 4) {
        CONSUME(u0, av0); LOADSLOT(i + 4, u0, av0);
        CONSUME(u1, av1); LOADSLOT(i + 5, u1, av1);
        CONSUME(u2, av2); LOADSLOT(i + 6, u2, av2);
        CONSUME(u3, av3); LOADSLOT(i + 7, u3, av3);
    }
    int rem = deg - i;                       // 1..7
    CONSUME(u0, av0); if (rem > 4) LOADSLOT(i + 4, u0, av0);
    if (rem > 1) { CONSUME(u1, av1); if (rem > 5) LOADSLOT(i + 5, u1, av1); }
    if (rem > 2) { CONSUME(u2, av2); if (rem > 6) LOADSLOT(i + 6, u2, av2); }
    if (rem > 3) CONSUME(u3, av3);
    if (rem > 4) CONSUME(u0, av0);
    if (rem > 5) CONSUME(u1, av1);
    if (rem > 6) CONSUME(u2, av2);
#undef LOADSLOT
#undef CONSUME

    float inv = 1.f / dacc;
    const int cb = 2 * UPL * lane;
    if (BF16OUT) {
        unsigned pk[UPL];
        #pragma unroll
        for (int q = 0; q < UPL; ++q) {
            float v0 = acc[2 * q] * inv + bias[cb + 2 * q];
            float v1 = acc[2 * q + 1] * inv + bias[cb + 2 * q + 1];
            if (RELU) { v0 = fmaxf(v0, 0.f); v1 = fmaxf(v1, 0.f); }
            pk[q] = (unsigned)f2bf(v0) | ((unsigned)f2bf(v1) << 16);
        }
        if (UPL == 4) {
            uint4 t; t.x = pk[0]; t.y = pk[1]; t.z = pk[2]; t.w = pk[3];
            ((uint4*)((unsigned*)out_v + (size_t)n * RU))[lane] = t;
        } else {
            ((unsigned*)out_v)[(size_t)n * RU + lane] = pk[0];
        }
    } else {
        #pragma unroll
        for (int q = 0; q < UPL; ++q) {
            float v0 = acc[2 * q] * inv + bias[cb + 2 * q];
            float v1 = acc[2 * q + 1] * inv + bias[cb + 2 * q + 1];
            if (RELU) { v0 = fmaxf(v0, 0.f); v1 = fmaxf(v1, 0.f); }
            float2 o; o.x = v0; o.y = v1;
            ((float2*)((float*)out_v + (size_t)n * F))[UPL * lane + q] = o;
        }
    }
}

// ---------------- host launch ----------------

extern "C" void kernel_launch(void* const* d_in, const int* in_sizes, int n_in,
                              void* d_out, int out_size, void* d_ws, size_t ws_size,
                              hipStream_t stream) {
    const float* x        = (const float*)d_in[0];
    const int*   ei       = (const int*)  d_in[1];
    const float* W1       = (const float*)d_in[2];
    const float* att_src1 = (const float*)d_in[3];
    const float* att_dst1 = (const float*)d_in[4];
    const float* b1       = (const float*)d_in[5];
    const float* W2       = (const float*)d_in[6];
    const float* att_src2 = (const float*)d_in[7];
    const float* att_dst2 = (const float*)d_in[8];
    const float* b2       = (const float*)d_in[9];
    const float* W3       = (const float*)d_in[10];
    const float* att_src3 = (const float*)d_in[11];
    const float* att_dst3 = (const float*)d_in[12];
    const float* b3       = (const float*)d_in[13];

    const int IN_FEATS = 256;
    const int N = in_sizes[0] / IN_FEATS;   // 30000
    const int E = in_sizes[1] / 2;          // 480000
    const int ET = E + N;
    const int NB = (N + 1023) / 1024;       // scan blocks (30)

    // workspace layout
    char* p = (char*)d_ws;
    unsigned short* h_bf    = (unsigned short*)p; p += (size_t)N * 512 * sizeof(unsigned short);
    unsigned short* act_bf  = (unsigned short*)p; p += (size_t)N * 512 * sizeof(unsigned short);
    unsigned short* x_bf    = (unsigned short*)p; p += (size_t)N * 256 * sizeof(unsigned short);
    float*          a_src   = (float*)p;          p += (size_t)N * 4 * sizeof(float);
    float*          a_dst   = (float*)p;          p += (size_t)N * 4 * sizeof(float);
    float*          wbuf    = (float*)p;          p += (size_t)ET * 4 * sizeof(float);
    unsigned short* W1T     = (unsigned short*)p; p += (size_t)512 * 256 * sizeof(unsigned short);
    unsigned short* W2T     = (unsigned short*)p; p += (size_t)512 * 512 * sizeof(unsigned short);
    unsigned short* W3T     = (unsigned short*)p; p += (size_t)128 * 512 * sizeof(unsigned short);
    int*            row_ptr = (int*)p;            p += ((size_t)N + 16) * sizeof(int);   // original space
    int*            row_ptr_s = (int*)p;          p += ((size_t)N + 16) * sizeof(int);   // sorted space
    int*            cursor  = (int*)p;            p += (size_t)N * sizeof(int);
    int*            dhist   = (int*)p;            p += 512 * sizeof(int);
    int*            dcur    = (int*)p;            p += 512 * sizeof(int);
    int*            node_order = (int*)p;         p += (size_t)N * sizeof(int);
    int*            inv_order  = (int*)p;         p += (size_t)N * sizeof(int);
    int*            sdeg    = (int*)p;            p += (size_t)N * sizeof(int);
    int*            bsum    = (int*)p;            p += 64 * sizeof(int);
    unsigned short* csr_src = (unsigned short*)p; p += (size_t)ET * sizeof(unsigned short);
    unsigned short* csr_dpos = (unsigned short*)p; p += (size_t)ET * sizeof(unsigned short);

    // ---- prep: W transposes + hist; CSR build (orig) -> rank -> CSR (sorted)
    hipMemsetAsync(cursor, 0, ((size_t)N + 512) * sizeof(int), stream); // cursor+dhist
    {
        int total = 256 * 512 + 512 * 512 + 512 * 128 + E;
        prep_hist_kernel<<<(total + 255) / 256, 256, 0, stream>>>(
            W1, W1T, W2, W2T, W3, W3T, ei, cursor, E);
    }
    hist_kernel<<<(N + 255) / 256, 256, 0, stream>>>(cursor, dhist, N);
    scan_bsum_kernel<<<NB, 1024, 0, stream>>>(cursor, bsum, N);
    scan_final_kernel<<<NB, 1024, 0, stream>>>(cursor, bsum, row_ptr, N, NB);
    deg_scan_kernel<<<1, 512, 0, stream>>>(dhist, dcur);
    rank_kernel<<<(N + 255) / 256, 256, 0, stream>>>(row_ptr, dcur, node_order, inv_order, sdeg, N);
    // second scan: sorted-space row_ptr_s + write cursors (sdeg -> cursors)
    scan_bsum_kernel<<<NB, 1024, 0, stream>>>(sdeg, bsum, N);
    scan_final_kernel<<<NB, 1024, 0, stream>>>(sdeg, bsum, row_ptr_s, N, NB);
    {
        int total = E + N + N * 64;          // edges + self-loops + x float4s
        scatter_xcast_kernel<<<(total + 255) / 256, 256, 0, stream>>>(
            ei, sdeg, csr_src, csr_dpos, node_order, inv_order, x, x_bf, E, N);
    }

    const int MB128 = (N + 127) / 128;      // 235
    const int MB256 = (N + 255) / 256;      // 118
    const int NC32 = (N + 31) / 32;         // node chunks (sliced agg)
    const int NB4 = (N + 3) / 4;            // 4 waves/block (full agg)
    const int EB = (ET + 255) / 256;        // weight-kernel blocks

    // ---- Layer 1: sliced agg A' (precomputed weights) ----
    mfma_gemm_kernel<128, 256><<<dim3(2, MB128), 512, 0, stream>>>(x_bf, W1T, h_bf, att_src1, att_dst1, a_src, a_dst, 4, N, 512, 256);
    weight_kernel<4><<<EB, 256, 0, stream>>>(csr_src, csr_dpos, a_src, a_dst, wbuf, ET, N);
    agg_kernel<512, 4, 8, true, true><<<8 * NC32, 256, 0, stream>>>((const unsigned*)h_bf, wbuf, row_ptr_s, csr_src, node_order, b1, act_bf, ET, N);

    // ---- Layer 2: full-row agg B (control) ----
    mfma_gemm_kernel<128, 256><<<dim3(2, MB128), 512, 0, stream>>>(act_bf, W2T, h_bf, att_src2, att_dst2, a_src, a_dst, 4, N, 512, 512);
    agg_full_kernel<512, 4, true, true><<<NB4, 256, 0, stream>>>((const unsigned*)h_bf, a_src, a_dst, row_ptr_s, csr_src, b2, act_bf, N);

    // ---- Layer 3: sliced agg A' (H=1), fp32 out (original order) ----
    mfma_gemm_kernel<256, 128><<<dim3(1, MB256), 512, 0, stream>>>(act_bf, W3T, h_bf, att_src3, att_dst3, a_src, a_dst, 1, N, 128, 512);
    weight_kernel<1><<<EB, 256, 0, stream>>>(csr_src, csr_dpos, a_src, a_dst, wbuf, ET, N);
    agg_kernel<128, 1, 2, false, false><<<2 * NC32, 256, 0, stream>>>((const unsigned*)h_bf, wbuf, row_ptr_s, csr_src, node_order, b3, d_out, ET, N);
}